// Round 5
// baseline (289.681 us; speedup 1.0000x reference)
//
#include <hip/hip_runtime.h>

// Problem constants: B=2, C=256, planes=64, T=8, D=H=W=16
// spatial per batch S = T*D*H*W = 32768
#define S_TOT 32768

typedef unsigned short ushortT;
typedef __attribute__((ext_vector_type(8))) short short8;
typedef __attribute__((ext_vector_type(4))) float floatx4;
typedef __attribute__((ext_vector_type(16))) float floatx16;

__device__ __forceinline__ ushortT f2bf(float f) {
    unsigned u = __float_as_uint(f);
    u = (u + 0x7fffu + ((u >> 16) & 1u)) >> 16;
    return (ushortT)u;
}
__device__ __forceinline__ float bf2f(ushortT h) {
    return __uint_as_float(((unsigned)h) << 16);
}

// ---------------------------------------------------------------------------
// Prep weights:
//  w1 -> wb1 [cc(8)][q(4)][o(64)][j(8)]            (c = cc*32+q*8+j)   16x16x32 A
//  w2 -> wb2 [tap(81)][ks(4)][half(2)][o(64)][j(8)] (c = ks*16+half*8+j) 32x32x16 A
//  w3 -> wb3 [g(8)][o(256)][j(8)]                  (g=ks*4+q, c=ks*32+q*8+j)
__global__ __launch_bounds__(256) void k_prep_w(const float* __restrict__ w1,
                                                const float* __restrict__ w2,
                                                const float* __restrict__ w3,
                                                ushortT* __restrict__ wb1,
                                                ushortT* __restrict__ wb2,
                                                ushortT* __restrict__ wb3) {
    int idx = blockIdx.x * 256 + threadIdx.x;
    if (idx < 16384) {
        int e = idx;
        int j = e & 7, o = (e >> 3) & 63, q = (e >> 9) & 3, cc = e >> 11;
        int c = cc * 32 + q * 8 + j;
        wb1[e] = f2bf(w1[o * 256 + c]);
    } else if (idx < 16384 + 331776) {
        int e = idx - 16384;
        int j = e & 7, o = (e >> 3) & 63, half = (e >> 9) & 1, ks = (e >> 10) & 3,
            tap = e >> 12;
        int c = ks * 16 + half * 8 + j;
        wb2[e] = f2bf(w2[((size_t)o * 64 + c) * 81 + tap]);
    } else if (idx < 16384 + 331776 + 16384) {
        int e = idx - 348160;
        int j = e & 7, o = (e >> 3) & 255, g = e >> 11;
        int ks = g >> 2, q = g & 3;
        int c = ks * 32 + q * 8 + j;
        wb3[e] = f2bf(w3[o * 64 + c]);
    }
}

// ---------------------------------------------------------------------------
// Reduce per-channel partials -> raw sum / sumsq. grid = nch.
__global__ __launch_bounds__(256) void k_reduce(const float* __restrict__ ps,
                                                const float* __restrict__ pq,
                                                int n,
                                                float* __restrict__ sum,
                                                float* __restrict__ sq) {
    __shared__ float red[8];
    int ch = blockIdx.x, tid = threadIdx.x;
    float s = 0.f, q = 0.f;
    for (int i = tid; i < n; i += 256) {
        s += ps[(size_t)ch * n + i];
        q += pq[(size_t)ch * n + i];
    }
#pragma unroll
    for (int off = 32; off; off >>= 1) {
        s += __shfl_down(s, off);
        q += __shfl_down(q, off);
    }
    int wid = tid >> 6;
    if ((tid & 63) == 0) { red[wid] = s; red[4 + wid] = q; }
    __syncthreads();
    if (tid == 0) {
        sum[ch] = red[0] + red[1] + red[2] + red[3];
        sq[ch]  = red[4] + red[5] + red[6] + red[7];
    }
}

// ---------------------------------------------------------------------------
// K1: conv1x1 256->64 via 16x16x32 MFMA; epilogue writes bf16 + bn1 partials.
__global__ __launch_bounds__(256) void k_conv1_mfma(const float* __restrict__ x,
                                                    const ushortT* __restrict__ wb1,
                                                    ushortT* __restrict__ y1bf,
                                                    float* __restrict__ p1s,
                                                    float* __restrict__ p1q) {
    __shared__ __align__(16) ushortT xb[128 * 40];   // [n][c32] stride 40

    int tid = threadIdx.x;
    int blk = blockIdx.x;
    int b  = blk >> 8;
    int n0 = (blk & 255) * 128;

    int lane = tid & 63;
    int wv   = tid >> 6;
    int m    = lane & 15;
    int q    = lane >> 4;

    int c_loc = tid & 31;
    int ng    = tid >> 5;

    floatx4 acc[8];
#pragma unroll
    for (int i = 0; i < 8; ++i) acc[i] = (floatx4){0.f, 0.f, 0.f, 0.f};

    for (int cc = 0; cc < 8; ++cc) {
        short8 afr = *(const short8*)(wb1 + (((cc * 4 + q) * 64) + wv * 16 + m) * 8);

        __syncthreads();
        {
            int c = cc * 32 + c_loc;
            const float* xp = x + ((size_t)(b * 256 + c)) * S_TOT + n0 + ng * 16;
#pragma unroll
            for (int k = 0; k < 4; ++k) {
                float4 v = *(const float4*)(xp + k * 4);
                int nb = ng * 16 + k * 4;
                xb[(nb + 0) * 40 + c_loc] = f2bf(v.x);
                xb[(nb + 1) * 40 + c_loc] = f2bf(v.y);
                xb[(nb + 2) * 40 + c_loc] = f2bf(v.z);
                xb[(nb + 3) * 40 + c_loc] = f2bf(v.w);
            }
        }
        __syncthreads();

#pragma unroll
        for (int pt = 0; pt < 8; ++pt) {
            short8 bfr = *(const short8*)(xb + (pt * 16 + m) * 40 + q * 8);
            acc[pt] = __builtin_amdgcn_mfma_f32_16x16x32_bf16(afr, bfr, acc[pt], 0, 0, 0);
        }
    }

#pragma unroll
    for (int pt = 0; pt < 8; ++pt) {
#pragma unroll
        for (int r = 0; r < 4; ++r) {
            int o = wv * 16 + q * 4 + r;
            y1bf[((size_t)(b * 64 + o)) * S_TOT + n0 + pt * 16 + m] = f2bf(acc[pt][r]);
        }
    }
    // bn1 partials: reduce over 16 m-lanes, one writer per (o, blk)
#pragma unroll
    for (int r = 0; r < 4; ++r) {
        float s = 0.f, sq_ = 0.f;
#pragma unroll
        for (int pt = 0; pt < 8; ++pt) {
            float v = acc[pt][r];
            s += v; sq_ += v * v;
        }
#pragma unroll
        for (int mask = 1; mask < 16; mask <<= 1) {
            s   += __shfl_xor(s, mask);
            sq_ += __shfl_xor(sq_, mask);
        }
        if (m == 0) {
            int o = wv * 16 + q * 4 + r;
            p1s[o * 512 + blk] = s;
            p1q[o * 512 + blk] = sq_;
        }
    }
}

// ---------------------------------------------------------------------------
// Prep: yout = bf16(relu(a*yin + b)), a/b computed inline from raw sums (nch=64)
__global__ __launch_bounds__(256) void k_prep(const ushortT* __restrict__ yin,
                                              const float* __restrict__ sum,
                                              const float* __restrict__ sq,
                                              const float* __restrict__ g,
                                              const float* __restrict__ bb,
                                              ushortT* __restrict__ yout) {
    size_t i = ((size_t)blockIdx.x * 256 + threadIdx.x) * 4;
    int c = (int)((i >> 15) & 63);
    const float inv_n = 1.f / 65536.f;
    float mean = sum[c] * inv_n;
    float var  = sq[c] * inv_n - mean * mean;
    float a  = g[c] * rsqrtf(var + 1e-5f);
    float bs = bb[c] - mean * a;
    ushort4 v = *(const ushort4*)(yin + i);
    ushort4 r;
    r.x = f2bf(fmaxf(a * bf2f(v.x) + bs, 0.f));
    r.y = f2bf(fmaxf(a * bf2f(v.y) + bs, 0.f));
    r.z = f2bf(fmaxf(a * bf2f(v.z) + bs, 0.f));
    r.w = f2bf(fmaxf(a * bf2f(v.w) + bs, 0.f));
    *(ushort4*)(yout + i) = r;
}

// ---------------------------------------------------------------------------
// K3: conv 3x3x3x3, 64->64 as 32x32x16 bf16 MFMA implicit GEMM.
// grid 512 = (b,t,d,h-half); block 256 = 4 waves. Wave wv owns pos-tile
// nt=wv (32 pos) and BOTH o-tiles (o=0..63): each B-frag LDS read feeds 2
// MFMAs. A-frags (2 ot x 4 ks per tap) from global (L2-hot, wave-shared).
// Epilogue: bf16 store + bn2 partials.
__global__ __launch_bounds__(256, 2) void k_conv2_mfma(
        const ushortT* __restrict__ y1n,   // [b][c][t][d][h][w] bf16
        const ushortT* __restrict__ wb2,   // [tap][ks][half][o][j] bf16
        ushortT* __restrict__ y2bf,
        float* __restrict__ p2s,
        float* __restrict__ p2q) {
    __shared__ __align__(16) ushortT xs[180 * 72];   // [ppos(10x18)][c64] stride 72

    int tid = threadIdx.x;
    int blk = blockIdx.x;
    int b  = blk >> 8;
    int t  = (blk >> 5) & 7;
    int d  = (blk >> 1) & 15;
    int h0 = (blk & 1) * 8;

    int lane = tid & 63;
    int wv   = tid >> 6;          // pos-tile: pos = wv*32 + (lane&31)
    int n32  = lane & 31;
    int half = lane >> 5;
    int hl   = (lane >> 4) & 1;   // = n32>>4
    int w    = lane & 15;

    int c2      = tid & 31;       // staging channels 2c2, 2c2+1
    int prbase  = tid >> 5;

    floatx16 acc0 = {0.f}, acc1 = {0.f};
#pragma unroll
    for (int i = 0; i < 16; ++i) { acc0[i] = 0.f; acc1[i] = 0.f; }

    const size_t cstride = 32768;
    uint32_t* xsd = (uint32_t*)xs;

    for (int ktd = 0; ktd < 9; ++ktd) {
        int kt = ktd / 3, kd = ktd - kt * 3;
        int tt = t + kt - 1;
        int dd = d + kd - 1;
        bool pv = (tt >= 0 && tt < 8 && dd >= 0 && dd < 16);

        __syncthreads();   // previous iteration's LDS reads complete

        // stage padded 10x18 plane x 64 c, transposed ([ppos][c])
        for (int pr = prbase; pr < 10; pr += 8) {
            int hin = h0 + pr - 1;
            uint32_t pack[18];
            if (pv && hin >= 0 && hin < 16) {
                const ushortT* p0 = y1n +
                    (((size_t)(b * 64 + 2 * c2) * 8 + tt) * 16 + dd) * 256 + hin * 16;
                const ushortT* p1 = p0 + cstride;
                uint4 r0 = *(const uint4*)p0;
                uint4 r1 = *(const uint4*)(p0 + 8);
                uint4 s0 = *(const uint4*)p1;
                uint4 s1 = *(const uint4*)(p1 + 8);
                uint32_t ra[8] = {r0.x, r0.y, r0.z, r0.w, r1.x, r1.y, r1.z, r1.w};
                uint32_t sa[8] = {s0.x, s0.y, s0.z, s0.w, s1.x, s1.y, s1.z, s1.w};
                pack[0] = 0; pack[17] = 0;
#pragma unroll
                for (int k = 0; k < 8; ++k) {
                    pack[1 + 2 * k] = (ra[k] & 0xffffu) | (sa[k] << 16);
                    pack[2 + 2 * k] = (ra[k] >> 16) | (sa[k] & 0xffff0000u);
                }
            } else {
#pragma unroll
                for (int k = 0; k < 18; ++k) pack[k] = 0;
            }
            int base = pr * 18 * 36 + c2;
#pragma unroll
            for (int k = 0; k < 18; ++k) xsd[base + k * 36] = pack[k];
        }
        __syncthreads();

#pragma unroll
        for (int khw = 0; khw < 9; ++khw) {
            const int kh = khw / 3, kw = khw - 3 * kh;
            int tap = ktd * 9 + khw;
            // A-frags: 2 o-tiles x 4 k-steps, 16B/lane, wave-uniform addresses
            short8 a0[4], a1[4];
#pragma unroll
            for (int ks = 0; ks < 4; ++ks) {
                const ushortT* wp = wb2 + ((size_t)(tap * 4 + ks) * 2 + half) * 512;
                a0[ks] = *(const short8*)(wp + n32 * 8);
                a1[ks] = *(const short8*)(wp + (32 + n32) * 8);
            }
            int ppos = (wv * 2 + hl + kh) * 18 + (w + kw);
            const ushortT* bp = xs + ppos * 72 + half * 8;
#pragma unroll
            for (int ks = 0; ks < 4; ++ks) {
                short8 bfr = *(const short8*)(bp + ks * 16);
                acc0 = __builtin_amdgcn_mfma_f32_32x32x16_bf16(a0[ks], bfr, acc0, 0, 0, 0);
                acc1 = __builtin_amdgcn_mfma_f32_32x32x16_bf16(a1[ks], bfr, acc1, 0, 0, 0);
            }
        }
    }

    // store bf16: C layout col=lane&31 (pos), row=(r&3)+8*(r>>2)+4*half
    size_t pb = (((size_t)(b * 64) * 8 + t) * 16 + d) * 256 +
                (h0 + wv * 2 + hl) * 16 + w;
#pragma unroll
    for (int r = 0; r < 16; ++r) {
        int row = (r & 3) + 8 * (r >> 2) + 4 * half;
        y2bf[pb + (size_t)row * S_TOT]        = f2bf(acc0[r]);
        y2bf[pb + (size_t)(32 + row) * S_TOT] = f2bf(acc1[r]);
    }
    // bn2 partials: reduce over the 32 pos-lanes; writers n32==0 (lanes 0,32)
#pragma unroll
    for (int r = 0; r < 16; ++r) {
        float s0 = acc0[r], q0 = s0 * s0;
        float s1 = acc1[r], q1 = s1 * s1;
#pragma unroll
        for (int mask = 1; mask < 32; mask <<= 1) {
            s0 += __shfl_xor(s0, mask); q0 += __shfl_xor(q0, mask);
            s1 += __shfl_xor(s1, mask); q1 += __shfl_xor(q1, mask);
        }
        if (n32 == 0) {
            int row = (r & 3) + 8 * (r >> 2) + 4 * half;
            int pi = blk * 4 + wv;
            p2s[row * 2048 + pi]        = s0;
            p2q[row * 2048 + pi]        = q0;
            p2s[(32 + row) * 2048 + pi] = s1;
            p2q[(32 + row) * 2048 + pi] = q1;
        }
    }
}

// ---------------------------------------------------------------------------
// K5: conv1x1 64->256 via MFMA; applies bn2+relu inline while staging y2bf;
// writes y3 fp32 (into d_out) + bn3 partials.
__global__ __launch_bounds__(256) void k_conv3_mfma(const ushortT* __restrict__ y2bf,
                                                    const ushortT* __restrict__ wb3,
                                                    const float* __restrict__ sum2,
                                                    const float* __restrict__ sq2,
                                                    const float* __restrict__ g2,
                                                    const float* __restrict__ b2,
                                                    float* __restrict__ y3,
                                                    float* __restrict__ p3s,
                                                    float* __restrict__ p3q) {
    __shared__ __align__(16) ushortT yb[64 * 72];   // [n][c64] stride 72

    int tid = threadIdx.x;
    int blk = blockIdx.x;
    int b  = blk >> 9;
    int n0 = (blk & 511) * 64;

    int lane = tid & 63;
    int wv   = tid >> 6;
    int m    = lane & 15;
    int q    = lane >> 4;

    const float inv_n = 1.f / 65536.f;
    // stage y2bf with bn2+relu applied: 64 n x 64 c, transposed
    for (int idx = tid; idx < 512; idx += 256) {
        int c = idx >> 3, k = idx & 7;
        float mean = sum2[c] * inv_n;
        float var  = sq2[c] * inv_n - mean * mean;
        float a  = g2[c] * rsqrtf(var + 1e-5f);
        float bs = b2[c] - mean * a;
        uint4 v = *(const uint4*)(y2bf + ((size_t)(b * 64 + c)) * S_TOT + n0 + k * 8);
        uint32_t va[4] = {v.x, v.y, v.z, v.w};
#pragma unroll
        for (int p = 0; p < 4; ++p) {
            float lo = fmaxf(a * bf2f((ushortT)(va[p] & 0xffffu)) + bs, 0.f);
            float hi = fmaxf(a * bf2f((ushortT)(va[p] >> 16)) + bs, 0.f);
            yb[(k * 8 + 2 * p)     * 72 + c] = f2bf(lo);
            yb[(k * 8 + 2 * p + 1) * 72 + c] = f2bf(hi);
        }
    }
    __syncthreads();

    floatx4 acc[4][4];
#pragma unroll
    for (int i = 0; i < 4; ++i)
#pragma unroll
        for (int j = 0; j < 4; ++j) acc[i][j] = (floatx4){0.f, 0.f, 0.f, 0.f};

#pragma unroll
    for (int ks = 0; ks < 2; ++ks) {
        short8 afr[4];
#pragma unroll
        for (int ot = 0; ot < 4; ++ot)
            afr[ot] = *(const short8*)(wb3 +
                (((ks * 4 + q) * 256) + wv * 64 + ot * 16 + m) * 8);
#pragma unroll
        for (int pt = 0; pt < 4; ++pt) {
            short8 bfr = *(const short8*)(yb + (pt * 16 + m) * 72 + ks * 32 + q * 8);
#pragma unroll
            for (int ot = 0; ot < 4; ++ot)
                acc[ot][pt] = __builtin_amdgcn_mfma_f32_16x16x32_bf16(
                    afr[ot], bfr, acc[ot][pt], 0, 0, 0);
        }
    }

    // store fp32 + bn3 partials
#pragma unroll
    for (int ot = 0; ot < 4; ++ot) {
#pragma unroll
        for (int pt = 0; pt < 4; ++pt) {
#pragma unroll
            for (int r = 0; r < 4; ++r) {
                int o = wv * 64 + ot * 16 + q * 4 + r;
                y3[((size_t)(b * 256 + o)) * S_TOT + n0 + pt * 16 + m] = acc[ot][pt][r];
            }
        }
    }
#pragma unroll
    for (int ot = 0; ot < 4; ++ot) {
#pragma unroll
        for (int r = 0; r < 4; ++r) {
            float s = 0.f, sq_ = 0.f;
#pragma unroll
            for (int pt = 0; pt < 4; ++pt) {
                float v = acc[ot][pt][r];
                s += v; sq_ += v * v;
            }
#pragma unroll
            for (int mask = 1; mask < 16; mask <<= 1) {
                s   += __shfl_xor(s, mask);
                sq_ += __shfl_xor(sq_, mask);
            }
            if (m == 0) {
                int o = wv * 64 + ot * 16 + q * 4 + r;
                p3s[o * 1024 + blk] = s;
                p3q[o * 1024 + blk] = sq_;
            }
        }
    }
}

// ---------------------------------------------------------------------------
// K7: out = relu(bn3(y3) + x), in place on d_out; bn3 scale/shift inline.
__global__ __launch_bounds__(256) void k_final(const float* __restrict__ x,
                                               const float* __restrict__ sum,
                                               const float* __restrict__ sq,
                                               const float* __restrict__ g,
                                               const float* __restrict__ bb,
                                               float* __restrict__ out) {
    size_t i = ((size_t)blockIdx.x * 256 + threadIdx.x) * 4;
    int o = (int)((i >> 15) & 255);
    const float inv_n = 1.f / 65536.f;
    float mean = sum[o] * inv_n;
    float var  = sq[o] * inv_n - mean * mean;
    float a  = g[o] * rsqrtf(var + 1e-5f);
    float bs = bb[o] - mean * a;
    float4 y  = *(float4*)(out + i);
    float4 xv = *(const float4*)(x + i);
    float4 r;
    r.x = fmaxf(a * y.x + bs + xv.x, 0.f);
    r.y = fmaxf(a * y.y + bs + xv.y, 0.f);
    r.z = fmaxf(a * y.z + bs + xv.z, 0.f);
    r.w = fmaxf(a * y.w + bs + xv.w, 0.f);
    *(float4*)(out + i) = r;
}

// ---------------------------------------------------------------------------
extern "C" void kernel_launch(void* const* d_in, const int* in_sizes, int n_in,
                              void* d_out, int out_size, void* d_ws, size_t ws_size,
                              hipStream_t stream) {
    const float* x  = (const float*)d_in[0];
    const float* w1 = (const float*)d_in[1];
    const float* g1 = (const float*)d_in[2];
    const float* b1 = (const float*)d_in[3];
    const float* w2 = (const float*)d_in[4];
    const float* g2 = (const float*)d_in[5];
    const float* b2 = (const float*)d_in[6];
    const float* w3 = (const float*)d_in[7];
    const float* g3 = (const float*)d_in[8];
    const float* b3 = (const float*)d_in[9];

    char* ws = (char*)d_ws;
    ushortT* y1bf = (ushortT*)(ws);                  //  8 MiB
    ushortT* y1n  = (ushortT*)(ws + 8388608);        //  8 MiB
    ushortT* y2bf = (ushortT*)(ws + 16777216);       //  8 MiB
    ushortT* wb1  = (ushortT*)(ws + 25165824);       //  32 KiB
    ushortT* wb2  = (ushortT*)(ws + 25198592);       // 648 KiB
    ushortT* wb3  = (ushortT*)(ws + 25862144);       //  32 KiB
    float*   stats = (float*)(ws + 25894912);        // 768 floats (4 KiB slot)
    float* sum1 = stats;        float* sq1 = stats + 64;
    float* sum2 = stats + 128;  float* sq2 = stats + 192;
    float* sum3 = stats + 256;  float* sq3 = stats + 512;
    float* p1s = (float*)(ws + 25899008);            // 64*512   = 128 KiB
    float* p1q = (float*)(ws + 26030080);            // 128 KiB
    float* p2s = (float*)(ws + 26161152);            // 64*2048  = 512 KiB
    float* p2q = (float*)(ws + 26685440);            // 512 KiB
    float* p3s = (float*)(ws + 27209728);            // 256*1024 = 1 MiB
    float* p3q = (float*)(ws + 28258304);            // 1 MiB
    float* y3 = (float*)d_out;

    k_prep_w     <<<1424,  256, 0, stream>>>(w1, w2, w3, wb1, wb2, wb3);
    k_conv1_mfma <<<512,   256, 0, stream>>>(x, wb1, y1bf, p1s, p1q);
    k_reduce     <<<64,    256, 0, stream>>>(p1s, p1q, 512, sum1, sq1);
    k_prep       <<<4096,  256, 0, stream>>>(y1bf, sum1, sq1, g1, b1, y1n);
    k_conv2_mfma <<<512,   256, 0, stream>>>(y1n, wb2, y2bf, p2s, p2q);
    k_reduce     <<<64,    256, 0, stream>>>(p2s, p2q, 2048, sum2, sq2);
    k_conv3_mfma <<<1024,  256, 0, stream>>>(y2bf, wb3, sum2, sq2, g2, b2, y3, p3s, p3q);
    k_reduce     <<<256,   256, 0, stream>>>(p3s, p3q, 1024, sum3, sq3);
    k_final      <<<16384, 256, 0, stream>>>(x, sum3, sq3, g3, b3, y3);
}